// Round 8
// baseline (225.290 us; speedup 1.0000x reference)
//
#include <hip/hip_runtime.h>
#include <hip/hip_fp16.h>
#include <math.h>
#include <stdint.h>

// SupConLossTopK, K=8192, D=256, 64 labels, T=0.1, MAX_POS=6, NEG_K=30.
// Round 8: wave-per-anchor fused kernel (fixes round-7's 1-wave/SIMD
// latency exposure while keeping the fusion wins):
//  - k_prep : normalize -> fp16 Fh (blocks 0..K/4-1) + bucket sort (last
//             block); emits g_bucket + packed per-anchor int2 meta (bs,B).
//  - k_anchor: ONE WAVE PER ANCHOR (8192 waves = 8/SIMD). Anchor row in
//             512B wave-private LDS; positives: lane owns <=5 columns,
//             k-loop reads anchor chunk ONCE per k (32 wave-uniform LDS
//             b128 reads/wave, broadcast=free) against 5 independent 16B
//             gather streams (good MLP; clamped chunks collapse to one
//             broadcast line). Sims land in v[5] regs -> proven shfl_xor
//             argmax (6 passes). Negatives: with-replacement counter RNG
//             (round-7-validated, absmax 0.0), 4 lanes/dot, LDS reads are
//             4-address multicast (conflict-free). g_part[i] plain store.
//  - k_final: reduce 8192 partials -> mean.
// No g_sims round-trip, no same-address global atomics, 3 launches.
// Harness floor: ~44us 0xAA ws-poison + ~8us restore is inside dur_us.

#define NEGK 30
#define MAXP 6
#define MAXBC 320   // max bucket rows handled (actual ~128 +-11)

typedef _Float16 h2v __attribute__((ext_vector_type(2)));

__device__ __forceinline__ uint64_t mix64(uint64_t z) {
  z += 0x9E3779B97F4A7C15ULL;
  z = (z ^ (z >> 30)) * 0xBF58476D1CE4E5B9ULL;
  z = (z ^ (z >> 27)) * 0x94D049BB133111EBULL;
  return z ^ (z >> 31);
}

__device__ __forceinline__ float wave_reduce_add(float p) {
#pragma unroll
  for (int o = 32; o; o >>= 1) p += __shfl_down(p, o, 64);
  return p;  // lane 0
}

// dot of 8 packed halfs (one 16B chunk) accumulated into acc
__device__ __forceinline__ float dot8h(uint4 a, uint4 b, float acc) {
  const h2v* pa = (const h2v*)&a;
  const h2v* pb = (const h2v*)&b;
#if __has_builtin(__builtin_amdgcn_fdot2)
#pragma unroll
  for (int q = 0; q < 4; ++q) acc = __builtin_amdgcn_fdot2(pa[q], pb[q], acc, false);
#else
#pragma unroll
  for (int q = 0; q < 4; ++q)
    acc += (float)pa[q].x * (float)pb[q].x + (float)pa[q].y * (float)pb[q].y;
#endif
  return acc;
}

// ---- fused: blocks 0..K/4-1 normalize rows -> fp16; block K/4 bucket sort --
__global__ __launch_bounds__(256) void k_prep(const float* __restrict__ F,
                                              const int* __restrict__ labels, int K,
                                              __half* __restrict__ Fh,
                                              int* __restrict__ g_bucket,
                                              int2* __restrict__ g_meta) {
  __shared__ int cnt[64], start[65], cur[64];
  const int tid = threadIdx.x;

  if ((int)blockIdx.x < K / 4) {
    const int row = blockIdx.x * 4 + (tid >> 6);
    const int lane = tid & 63;
    const float4 a = ((const float4*)(F + (size_t)row * 256))[lane];
    float p = a.x * a.x + a.y * a.y + a.z * a.z + a.w * a.w;
    p = wave_reduce_add(p);
    p = __shfl(p, 0, 64);
    const float inv = 1.0f / fmaxf(sqrtf(p), 1e-12f);
    union { __half2 h[2]; uint2 u; } cv;
    cv.h[0] = __float22half2_rn(make_float2(a.x * inv, a.y * inv));
    cv.h[1] = __float22half2_rn(make_float2(a.z * inv, a.w * inv));
    ((uint2*)(Fh + (size_t)row * 256))[lane] = cv.u;
    return;
  }

  // bucket block
  if (tid < 64) cnt[tid] = 0;
  __syncthreads();
  for (int t = tid; t < K; t += 256) atomicAdd(&cnt[labels[t] & 63], 1);
  __syncthreads();
  if (tid == 0) {
    int acc = 0;
    for (int l = 0; l < 64; ++l) { start[l] = acc; acc += cnt[l]; }
    start[64] = acc;
  }
  __syncthreads();
  if (tid < 64) cur[tid] = start[tid];
  __syncthreads();
  for (int t = tid; t < K; t += 256) {
    const int l = labels[t] & 63;
    const int p = atomicAdd(&cur[l], 1);
    g_bucket[p] = t;
    g_meta[t] = make_int2(start[l], cnt[l]);
  }
}

// ---- wave-per-anchor: positives (5 gather streams) + argmax + negatives ----
__global__ __launch_bounds__(256) void k_anchor(
    const __half* __restrict__ Fh, const int* __restrict__ g_bucket,
    const int2* __restrict__ g_meta, float* __restrict__ g_part, int K) {
  __shared__ uint4 sA[4 * 32];        // 4 waves x 512B anchor rows
  const int wv = threadIdx.x >> 6;
  const int lane = threadIdx.x & 63;
  const int i = blockIdx.x * 4 + wv;  // K multiple of 4

  const int2 mt = g_meta[i];          // (bucket_start, bucket_size)
  const int bs = mt.x, B = mt.y;
  const int Bc = B < MAXBC ? B : MAXBC;
  const int n_pos = B - 1;
  const int n_neg = K - B;

  // stage anchor row into wave-private LDS (within-wave dependency only)
  ((uint2*)sA)[wv * 64 + lane] = ((const uint2*)(Fh + (size_t)i * 256))[lane];
  const uint4* sw = sA + wv * 32;

  // ---- positives: lane owns columns lane+64c; anchor chunk read once/k ----
  const uint4* colp[5];
  int colgq[5];
#pragma unroll
  for (int c = 0; c < 5; ++c) {
    const int cc = c * 64 + lane;
    const int idx = bs + (cc < Bc ? cc : 0);  // invalid -> broadcast row
    const int gq = g_bucket[idx];
    colgq[c] = (cc < Bc) ? gq : -1;
    colp[c] = (const uint4*)(Fh + (size_t)gq * 256);
  }
  float acc[5];
#pragma unroll
  for (int c = 0; c < 5; ++c) acc[c] = 0.0f;
  for (int k = 0; k < 32; ++k) {
    const uint4 a = sw[k];            // wave-uniform LDS broadcast (free)
#pragma unroll
    for (int c = 0; c < 5; ++c) acc[c] = dot8h(colp[c][k], a, acc[c]);
  }
  float v[5];
#pragma unroll
  for (int c = 0; c < 5; ++c)
    v[c] = (colgq[c] >= 0 && colgq[c] != i) ? acc[c] * 10.0f : -3.4e38f;

  // take = min(n_pos, max(1, min(MAXP, n_neg))), 0 if row invalid
  int t6 = n_neg < MAXP ? n_neg : MAXP;
  if (t6 < 1) t6 = 1;
  int take = n_pos < t6 ? n_pos : t6;
  if (n_pos <= 0 || n_neg <= 0) take = 0;
  const int target = (take > 0) ? (n_neg < NEGK ? n_neg : NEGK) : 0;

  // ---- top-take positives: 5-reg argmax + shfl_xor butterfly ----
  float num = 0.0f;
  for (int r = 0; r < take; ++r) {
    float best = -3.4e38f;
    int bi = 0x7FFFFFFF;
#pragma unroll
    for (int c = 0; c < 5; ++c) {
      if (v[c] > best) { best = v[c]; bi = c * 64 + lane; }
    }
#pragma unroll
    for (int o = 1; o < 64; o <<= 1) {
      const float ov = __shfl_xor(best, o, 64);
      const int oi = __shfl_xor(bi, o, 64);
      if (ov > best || (ov == best && oi < bi)) { best = ov; bi = oi; }
    }
    num += expf(best);
    const int csel = bi >> 6;
    if ((bi & 63) == lane) {
#pragma unroll
      for (int c = 0; c < 5; ++c)
        if (c == csel) v[c] = -3.4e38f;
    }
  }

  // ---- negatives: with-replacement draws, 4 lanes per dot, 2 rounds ----
  const int s = lane & 3, g = lane >> 2;
  float e = 0.0f;
#pragma unroll
  for (int r = 0; r < 2; ++r) {
    const int n = r * 16 + g;         // draw index 0..31
    const bool pv = (n < target);
    const uint64_t z = mix64(((uint64_t)(uint32_t)i << 32) | (uint32_t)n);
    const unsigned int rdraw =
        (unsigned int)(((uint64_t)(uint32_t)z * (uint64_t)n_neg) >> 32);
    const int pos = (rdraw < (unsigned int)bs) ? (int)rdraw : (int)rdraw + B;
    const int j = pv ? g_bucket[pos] : 0;
    const uint4* fj = (const uint4*)(Fh + (size_t)j * 256);
    float d = 0.0f;
#pragma unroll
    for (int k = 0; k < 8; ++k)
      d = dot8h(fj[k * 4 + s], sw[k * 4 + s], d);  // LDS: 4-addr multicast
    d += __shfl_xor(d, 1, 64);
    d += __shfl_xor(d, 2, 64);
    if (s == 0 && pv) e += expf(d * 10.0f);
  }
  const float wsum = wave_reduce_add(e);

  if (lane == 0) {
    float ls = 0.0f;
    if (take > 0) {
      const float denom = num + wsum;
      float ratio = denom > 0.0f ? num / denom : 0.0f;
      ratio = fmaxf(ratio, 1e-8f);
      ls = -logf(ratio);
    }
    g_part[i] = ls;                   // plain store, no atomics
  }
}

// ---- reduce 8192 per-anchor losses -> mean ----
__global__ __launch_bounds__(1024) void k_final(const float* __restrict__ g_part,
                                                float* __restrict__ out, int K) {
  __shared__ float s[16];
  float p = 0.0f;
  for (int t = threadIdx.x; t < K; t += 1024) p += g_part[t];
  p = wave_reduce_add(p);
  if ((threadIdx.x & 63) == 0) s[threadIdx.x >> 6] = p;
  __syncthreads();
  if (threadIdx.x == 0) {
    float tot = 0.0f;
#pragma unroll
    for (int w = 0; w < 16; ++w) tot += s[w];
    out[0] = tot / (float)K;
  }
}

extern "C" void kernel_launch(void* const* d_in, const int* in_sizes, int n_in,
                              void* d_out, int out_size, void* d_ws, size_t ws_size,
                              hipStream_t stream) {
  (void)n_in; (void)out_size; (void)ws_size;
  const float* F = (const float*)d_in[0];
  const int* labels = (const int*)d_in[1];
  const int K = in_sizes[1];  // 8192; D=256 hard-assumed
  float* out = (float*)d_out;

  char* ws = (char*)d_ws;
  size_t off = 0;
  int*   g_bucket = (int*)(ws + off);   off += (size_t)K * 4;
  float* g_part   = (float*)(ws + off); off += (size_t)K * 4;
  off = (off + 255) & ~(size_t)255;
  int2*  g_meta   = (int2*)(ws + off);  off += (size_t)K * 8;
  __half* Fh      = (__half*)(ws + off); off += (size_t)K * 256 * 2;

  k_prep<<<K / 4 + 1, 256, 0, stream>>>(F, labels, K, Fh, g_bucket, g_meta);
  k_anchor<<<K / 4, 256, 0, stream>>>(Fh, g_bucket, g_meta, g_part, K);
  k_final<<<1, 1024, 0, stream>>>(g_part, out, K);
}

// Round 9
// 127.824 us; speedup vs baseline: 1.7625x; 1.7625x over previous
//
#include <hip/hip_runtime.h>
#include <hip/hip_fp16.h>
#include <math.h>
#include <stdint.h>

// SupConLossTopK, K=8192, D=256, 64 labels, T=0.1, MAX_POS=6, NEG_K=30.
// Round 9 = round-6 split structure (best: 122us) with both hot kernels
// micro-optimized:
//  - k_gram v6: v5 was LDS-pipe-bound (one ds_read_b128 @12cy per dot8h
//    @8cy VALU). Lane now owns ceil(Bc/64) column streams (templated, 2 for
//    typical Bc~128), so each anchor-chunk LDS read feeds 2+ dots ->
//    VALU-bound. 8-row reuse per gather kept (round-8 lesson: gathered 16B
//    streams must amortize over >=8 anchors or L1 line-request rate binds).
//  - k_anchor v7: dedup dropped (with-replacement validated r7/r8, absmax
//    0.0); value-only argmax (exclude-by-equality, no index shuffles);
//    negatives as two independent load/dot chains (16 gathers in flight);
//    meta int4 (bs,B,loc,soff) single load.
//  - no same-address global atomics anywhere (round-4 lesson).
// exp(sim - rowmax) ratios == exp(sim) ratios -> no rowmax pass.
// Harness floor: ~44us 0xAA ws-poison + ~8us restore inside dur_us.

#define NEGK 30
#define MAXP 6
#define MAXBC 320   // max bucket rows (actual ~128 +-11; P(>320) ~ 1e-60)
#define RGB 32      // gram anchors (rows) per block, 8 per wave

typedef _Float16 h2v __attribute__((ext_vector_type(2)));

__device__ __forceinline__ uint64_t mix64(uint64_t z) {
  z += 0x9E3779B97F4A7C15ULL;
  z = (z ^ (z >> 30)) * 0xBF58476D1CE4E5B9ULL;
  z = (z ^ (z >> 27)) * 0x94D049BB133111EBULL;
  return z ^ (z >> 31);
}

__device__ __forceinline__ float wave_reduce_add(float p) {
#pragma unroll
  for (int o = 32; o; o >>= 1) p += __shfl_down(p, o, 64);
  return p;  // lane 0
}

// dot of 8 packed halfs (one 16B chunk) accumulated into acc
__device__ __forceinline__ float dot8h(uint4 a, uint4 b, float acc) {
  const h2v* pa = (const h2v*)&a;
  const h2v* pb = (const h2v*)&b;
#if __has_builtin(__builtin_amdgcn_fdot2)
#pragma unroll
  for (int q = 0; q < 4; ++q) acc = __builtin_amdgcn_fdot2(pa[q], pb[q], acc, false);
#else
#pragma unroll
  for (int q = 0; q < 4; ++q)
    acc += (float)pa[q].x * (float)pb[q].x + (float)pa[q].y * (float)pb[q].y;
#endif
  return acc;
}

// ---- fused: blocks 0..K/4-1 normalize rows -> fp16; block K/4 bucket sort --
__global__ __launch_bounds__(256) void k_prep(const float* __restrict__ F,
                                              const int* __restrict__ labels, int K,
                                              __half* __restrict__ Fh,
                                              int* __restrict__ g_start,
                                              int* __restrict__ g_soff,
                                              int* __restrict__ g_bucket,
                                              int4* __restrict__ g_meta) {
  __shared__ int cnt[64], start[65], cur[64], soff_s[64];
  const int tid = threadIdx.x;

  if ((int)blockIdx.x < K / 4) {
    const int row = blockIdx.x * 4 + (tid >> 6);
    const int lane = tid & 63;
    const float4 a = ((const float4*)(F + (size_t)row * 256))[lane];
    float p = a.x * a.x + a.y * a.y + a.z * a.z + a.w * a.w;
    p = wave_reduce_add(p);
    p = __shfl(p, 0, 64);
    const float inv = 1.0f / fmaxf(sqrtf(p), 1e-12f);
    union { __half2 h[2]; uint2 u; } cv;
    cv.h[0] = __float22half2_rn(make_float2(a.x * inv, a.y * inv));
    cv.h[1] = __float22half2_rn(make_float2(a.z * inv, a.w * inv));
    ((uint2*)(Fh + (size_t)row * 256))[lane] = cv.u;
    return;
  }

  // bucket block
  if (tid < 64) cnt[tid] = 0;
  __syncthreads();
  for (int t = tid; t < K; t += 256) atomicAdd(&cnt[labels[t] & 63], 1);
  __syncthreads();
  if (tid == 0) {
    int acc = 0, sacc = 0;
    for (int l = 0; l < 64; ++l) {
      start[l] = acc;
      const int B = cnt[l];
      acc += B;
      soff_s[l] = sacc;
      const int Bc = B < MAXBC ? B : MAXBC;
      sacc += Bc * Bc;
    }
    start[64] = acc;
  }
  __syncthreads();
  if (tid < 64) { cur[tid] = start[tid]; g_soff[tid] = soff_s[tid]; }
  if (tid < 65) g_start[tid] = start[tid];
  __syncthreads();
  for (int t = tid; t < K; t += 256) {
    const int l = labels[t] & 63;
    const int p = atomicAdd(&cur[l], 1);
    g_bucket[p] = t;
    g_meta[t] = make_int4(start[l], cnt[l], p - start[l], soff_s[l]);
  }
}

// ---- k_gram compute body: NCS column streams per lane ----
template <int NCS>
__device__ __forceinline__ void gram_body(const __half* __restrict__ Fh,
                                          const int* __restrict__ g_bucket,
                                          const uint4* __restrict__ sw,
                                          float* __restrict__ outb,
                                          int bs, int Bc, int r0w, int lane) {
  const uint4* cp[NCS];
  int cq[NCS];
#pragma unroll
  for (int cs = 0; cs < NCS; ++cs) {
    const int cc = cs * 64 + lane;
    const bool valid = (cc < Bc);
    const int gq = g_bucket[bs + (valid ? cc : 0)];
    cq[cs] = valid ? cc : -1;
    cp[cs] = (const uint4*)(Fh + (size_t)gq * 256);
  }

  float acc[8][NCS];
#pragma unroll
  for (int r = 0; r < 8; ++r)
#pragma unroll
    for (int cs = 0; cs < NCS; ++cs) acc[r][cs] = 0.0f;

  for (int k = 0; k < 32; k += 2) {
    uint4 c0[NCS], c1[NCS];
#pragma unroll
    for (int cs = 0; cs < NCS; ++cs) { c0[cs] = cp[cs][k]; c1[cs] = cp[cs][k + 1]; }
#pragma unroll
    for (int r = 0; r < 8; ++r) {
      const uint4 a0 = sw[r * 32 + k];      // wave-uniform LDS broadcast
      const uint4 a1 = sw[r * 32 + k + 1];
#pragma unroll
      for (int cs = 0; cs < NCS; ++cs) {
        acc[r][cs] = dot8h(c0[cs], a0, acc[r][cs]);
        acc[r][cs] = dot8h(c1[cs], a1, acc[r][cs]);
      }
    }
  }

#pragma unroll
  for (int r = 0; r < 8; ++r) {
    const int rr = r0w + r;
    if (rr < Bc) {
#pragma unroll
      for (int cs = 0; cs < NCS; ++cs) {
        const int cc = cq[cs];
        if (cc >= 0)
          outb[(size_t)rr * Bc + cc] = (rr == cc) ? -3.0e38f : acc[r][cs] * 10.0f;
      }
    }
  }
}

// ---- per-bucket Gram (sim*10, diag=-3e38): 32-row blocks, full col span ----
__global__ __launch_bounds__(256) void k_gram(const __half* __restrict__ Fh,
                                              const int* __restrict__ g_start,
                                              const int* __restrict__ g_soff,
                                              const int* __restrict__ g_bucket,
                                              float* __restrict__ g_sims) {
  __shared__ uint4 sA[RGB * 32];  // 32 rows x 512B = 16KB

  const int b  = blockIdx.x;
  const int bs = g_start[b];
  const int B  = g_start[b + 1] - bs;
  const int Bc = B < MAXBC ? B : MAXBC;
  const int r0 = blockIdx.y * RGB;
  if (r0 >= Bc) return;
  const int tid = threadIdx.x;

  // stage 32 anchor rows (clamped for OOB; their stores are skipped)
  for (int u = tid; u < RGB * 32; u += 256) {
    const int r = u >> 5, c = u & 31;
    const int rr = r0 + r;
    const int gr = g_bucket[bs + (rr < Bc ? rr : 0)];
    sA[u] = ((const uint4*)(Fh + (size_t)gr * 256))[c];
  }
  __syncthreads();

  const int wv = tid >> 6, lane = tid & 63;
  const uint4* sw = sA + (wv * 8) * 32;   // this wave's 8 anchor rows
  float* outb = g_sims + g_soff[b];
  const int r0w = r0 + wv * 8;

  if (Bc <= 128)
    gram_body<2>(Fh, g_bucket, sw, outb, bs, Bc, r0w, lane);
  else
    gram_body<5>(Fh, g_bucket, sw, outb, bs, Bc, r0w, lane);
}

// ---- per-anchor: one wave; value-only argmax + dual-chain negatives ----
__global__ __launch_bounds__(256) void k_anchor(
    const __half* __restrict__ Fh, const int* __restrict__ g_bucket,
    const int4* __restrict__ g_meta, const float* __restrict__ g_sims,
    float* __restrict__ g_part, int K) {
  __shared__ uint4 sA[4 * 32];        // 4 waves x 512B anchor rows
  const int wv = threadIdx.x >> 6;
  const int lane = threadIdx.x & 63;
  const int i = blockIdx.x * 4 + wv;  // K multiple of 4

  // stage anchor row into wave-private LDS (independent of meta)
  ((uint2*)sA)[wv * 64 + lane] = ((const uint2*)(Fh + (size_t)i * 256))[lane];
  const uint4* sw = sA + wv * 32;

  const int4 mt = g_meta[i];          // (bucket_start, bucket_size, loc, soff)
  const int bs = mt.x, B = mt.y;
  const int Bc = B < MAXBC ? B : MAXBC;
  int loc = mt.z;
  if (loc >= Bc) loc = 0;             // unreachable in practice
  const int n_pos = B - 1;
  const int n_neg = K - B;
  const float* simrow = g_sims + mt.w + (size_t)loc * Bc;

  // sim row -> 5 registers (Bc <= 320)
  float v[5];
#pragma unroll
  for (int rr = 0; rr < 5; ++rr) {
    const int t = lane + rr * 64;
    v[rr] = (t < Bc) ? simrow[t] : -3.4e38f;
  }

  int t6 = n_neg < MAXP ? n_neg : MAXP;
  if (t6 < 1) t6 = 1;
  int take = n_pos < t6 ? n_pos : t6;
  if (n_pos <= 0 || n_neg <= 0) take = 0;
  const int target = (take > 0) ? (n_neg < NEGK ? n_neg : NEGK) : 0;

  // ---- negatives first (kick off the gathers): dual independent chains ----
  const int s = lane & 3, g = lane >> 2;
  const int n0 = g, n1 = 16 + g;
  const uint64_t z0 = mix64(((uint64_t)(uint32_t)i << 32) | (uint32_t)n0);
  const uint64_t z1 = mix64(((uint64_t)(uint32_t)i << 32) | (uint32_t)n1);
  const unsigned int r0 = (unsigned int)(((uint64_t)(uint32_t)z0 * (uint64_t)n_neg) >> 32);
  const unsigned int r1 = (unsigned int)(((uint64_t)(uint32_t)z1 * (uint64_t)n_neg) >> 32);
  const int pos0 = (r0 < (unsigned int)bs) ? (int)r0 : (int)r0 + B;
  const int pos1 = (r1 < (unsigned int)bs) ? (int)r1 : (int)r1 + B;
  const bool pv0 = (n0 < target), pv1 = (n1 < target);
  const int j0 = pv0 ? g_bucket[pos0] : 0;
  const int j1 = pv1 ? g_bucket[pos1] : 0;
  const uint4* f0 = (const uint4*)(Fh + (size_t)j0 * 256);
  const uint4* f1 = (const uint4*)(Fh + (size_t)j1 * 256);
  float d0 = 0.0f, d1 = 0.0f;
#pragma unroll
  for (int k = 0; k < 8; ++k) {
    const uint4 aw = sw[k * 4 + s];   // LDS 4-address multicast (conflict-free)
    d0 = dot8h(f0[k * 4 + s], aw, d0);
    d1 = dot8h(f1[k * 4 + s], aw, d1);
  }
  d0 += __shfl_xor(d0, 1, 64); d0 += __shfl_xor(d0, 2, 64);
  d1 += __shfl_xor(d1, 1, 64); d1 += __shfl_xor(d1, 2, 64);
  float e = 0.0f;
  if (s == 0) {
    if (pv0) e += expf(d0 * 10.0f);
    if (pv1) e += expf(d1 * 10.0f);
  }
  const float wsum = wave_reduce_add(e);

  // ---- top-take positives: value-only max + exclude-by-equality ----
  float num = 0.0f;
  for (int r = 0; r < take; ++r) {
    float best = v[0];
#pragma unroll
    for (int c = 1; c < 5; ++c) best = fmaxf(best, v[c]);
#pragma unroll
    for (int o = 1; o < 64; o <<= 1) best = fmaxf(best, __shfl_xor(best, o, 64));
    num += expf(best);
#pragma unroll
    for (int c = 0; c < 5; ++c)
      if (v[c] == best) v[c] = -3.4e38f;
  }

  if (lane == 0) {
    float ls = 0.0f;
    if (take > 0) {
      const float denom = num + wsum;
      float ratio = denom > 0.0f ? num / denom : 0.0f;
      ratio = fmaxf(ratio, 1e-8f);
      ls = -logf(ratio);
    }
    g_part[i] = ls;                   // plain store, no atomics
  }
}

// ---- reduce 8192 per-anchor losses -> mean ----
__global__ __launch_bounds__(1024) void k_final(const float* __restrict__ g_part,
                                                float* __restrict__ out, int K) {
  __shared__ float s[16];
  float p = 0.0f;
  for (int t = threadIdx.x; t < K; t += 1024) p += g_part[t];
  p = wave_reduce_add(p);
  if ((threadIdx.x & 63) == 0) s[threadIdx.x >> 6] = p;
  __syncthreads();
  if (threadIdx.x == 0) {
    float tot = 0.0f;
#pragma unroll
    for (int w = 0; w < 16; ++w) tot += s[w];
    out[0] = tot / (float)K;
  }
}

extern "C" void kernel_launch(void* const* d_in, const int* in_sizes, int n_in,
                              void* d_out, int out_size, void* d_ws, size_t ws_size,
                              hipStream_t stream) {
  (void)n_in; (void)out_size; (void)ws_size;
  const float* F = (const float*)d_in[0];
  const int* labels = (const int*)d_in[1];
  const int K = in_sizes[1];  // 8192; D=256 hard-assumed
  float* out = (float*)d_out;

  char* ws = (char*)d_ws;
  size_t off = 0;
  int*   g_start  = (int*)(ws + off);   off += 512;
  int*   g_soff   = (int*)(ws + off);   off += 256;
  int*   g_bucket = (int*)(ws + off);   off += (size_t)K * 4;
  float* g_part   = (float*)(ws + off); off += (size_t)K * 4;
  off = (off + 255) & ~(size_t)255;
  int4*  g_meta   = (int4*)(ws + off);  off += (size_t)K * 16;
  __half* Fh      = (__half*)(ws + off); off += (size_t)K * 256 * 2;
  float* g_sims   = (float*)(ws + off);  off += (size_t)MAXBC * K * 4;

  k_prep<<<K / 4 + 1, 256, 0, stream>>>(F, labels, K, Fh, g_start, g_soff,
                                        g_bucket, g_meta);
  {
    dim3 grid(64, (MAXBC + RGB - 1) / RGB, 1);
    k_gram<<<grid, 256, 0, stream>>>(Fh, g_start, g_soff, g_bucket, g_sims);
  }
  k_anchor<<<K / 4, 256, 0, stream>>>(Fh, g_bucket, g_meta, g_sims, g_part, K);
  k_final<<<1, 1024, 0, stream>>>(g_part, out, K);
}

// Round 10
// 114.539 us; speedup vs baseline: 1.9669x; 1.1160x over previous
//
#include <hip/hip_runtime.h>
#include <hip/hip_fp16.h>
#include <math.h>
#include <stdint.h>

// SupConLossTopK, K=8192, D=256, 64 labels, T=0.1, MAX_POS=6, NEG_K=30.
// Round 10 = best-of-measured hybrid:
//  - k_prep : fused normalize->fp16 + bucket sort + int4 meta (r5/r6, 122us run)
//  - k_gram : EXACT round-6 version (32x64 tiles, grid 64x10x5, 8-row gather
//             amortization, wave-uniform LDS broadcasts) — the measured-best
//             gram; round-9's templated 2-stream variant regressed ~6us.
//  - k_anchor: round-9 version (strictly leaner than round-6's: no dedup
//             loop — with-replacement RNG validated r7/r8/r9 absmax 0.0;
//             value-only argmax; dual-chain negatives, 16 gathers in flight)
//  - k_final : 8192-float reduce -> mean
// No same-address global atomics anywhere (r4 lesson: 16k atomics+fences on
// one line == 204us). Gathered 16B streams amortized over >=8 anchor rows
// (r8 lesson: 1-row waves are L1-line-request-rate-bound).
// Harness floor inside dur_us: ~44us 0xAA poison of 256MiB ws (at HBM
// achievable ceiling) + input restore + 4 graph launches.
// exp(sim - rowmax) ratios == exp(sim) ratios -> no rowmax pass.

#define NEGK 30
#define MAXP 6
#define MAXBC 320   // max bucket rows (actual ~128 +-11; P(>320) ~ 1e-60)
#define RGB 32      // gram rows per block
#define CGB 64      // gram cols per block

typedef _Float16 h2v __attribute__((ext_vector_type(2)));

__device__ __forceinline__ uint64_t mix64(uint64_t z) {
  z += 0x9E3779B97F4A7C15ULL;
  z = (z ^ (z >> 30)) * 0xBF58476D1CE4E5B9ULL;
  z = (z ^ (z >> 27)) * 0x94D049BB133111EBULL;
  return z ^ (z >> 31);
}

__device__ __forceinline__ float wave_reduce_add(float p) {
#pragma unroll
  for (int o = 32; o; o >>= 1) p += __shfl_down(p, o, 64);
  return p;  // lane 0
}

// dot of 8 packed halfs (one 16B chunk) accumulated into acc
__device__ __forceinline__ float dot8h(uint4 a, uint4 b, float acc) {
  const h2v* pa = (const h2v*)&a;
  const h2v* pb = (const h2v*)&b;
#if __has_builtin(__builtin_amdgcn_fdot2)
#pragma unroll
  for (int q = 0; q < 4; ++q) acc = __builtin_amdgcn_fdot2(pa[q], pb[q], acc, false);
#else
#pragma unroll
  for (int q = 0; q < 4; ++q)
    acc += (float)pa[q].x * (float)pb[q].x + (float)pa[q].y * (float)pb[q].y;
#endif
  return acc;
}

// ---- fused: blocks 0..K/4-1 normalize rows -> fp16; block K/4 bucket sort --
__global__ __launch_bounds__(256) void k_prep(const float* __restrict__ F,
                                              const int* __restrict__ labels, int K,
                                              __half* __restrict__ Fh,
                                              int* __restrict__ g_start,
                                              int* __restrict__ g_soff,
                                              int* __restrict__ g_bucket,
                                              int4* __restrict__ g_meta) {
  __shared__ int cnt[64], start[65], cur[64], soff_s[64];
  const int tid = threadIdx.x;

  if ((int)blockIdx.x < K / 4) {
    const int row = blockIdx.x * 4 + (tid >> 6);
    const int lane = tid & 63;
    const float4 a = ((const float4*)(F + (size_t)row * 256))[lane];
    float p = a.x * a.x + a.y * a.y + a.z * a.z + a.w * a.w;
    p = wave_reduce_add(p);
    p = __shfl(p, 0, 64);
    const float inv = 1.0f / fmaxf(sqrtf(p), 1e-12f);
    union { __half2 h[2]; uint2 u; } cv;
    cv.h[0] = __float22half2_rn(make_float2(a.x * inv, a.y * inv));
    cv.h[1] = __float22half2_rn(make_float2(a.z * inv, a.w * inv));
    ((uint2*)(Fh + (size_t)row * 256))[lane] = cv.u;
    return;
  }

  // bucket block
  if (tid < 64) cnt[tid] = 0;
  __syncthreads();
  for (int t = tid; t < K; t += 256) atomicAdd(&cnt[labels[t] & 63], 1);
  __syncthreads();
  if (tid == 0) {
    int acc = 0, sacc = 0;
    for (int l = 0; l < 64; ++l) {
      start[l] = acc;
      const int B = cnt[l];
      acc += B;
      soff_s[l] = sacc;
      const int Bc = B < MAXBC ? B : MAXBC;
      sacc += Bc * Bc;
    }
    start[64] = acc;
  }
  __syncthreads();
  if (tid < 64) { cur[tid] = start[tid]; g_soff[tid] = soff_s[tid]; }
  if (tid < 65) g_start[tid] = start[tid];
  __syncthreads();
  for (int t = tid; t < K; t += 256) {
    const int l = labels[t] & 63;
    const int p = atomicAdd(&cur[l], 1);
    g_bucket[p] = t;
    g_meta[t] = make_int4(start[l], cnt[l], p - start[l], soff_s[l]);
  }
}

// ---- per-bucket Gram (sim*10, diag=-3e38): 32x64 tiles, 4 waves/block ----
// (exact round-6 structure — measured best)
__global__ __launch_bounds__(256) void k_gram(const __half* __restrict__ Fh,
                                              const int* __restrict__ g_start,
                                              const int* __restrict__ g_soff,
                                              const int* __restrict__ g_bucket,
                                              float* __restrict__ g_sims) {
  __shared__ uint4 sA[RGB * 32];  // 32 rows x 512B = 16KB

  const int b  = blockIdx.x;
  const int bs = g_start[b];
  const int B  = g_start[b + 1] - bs;
  const int Bc = B < MAXBC ? B : MAXBC;
  const int r0 = blockIdx.y * RGB;
  const int c0 = blockIdx.z * CGB;
  if (r0 >= Bc || c0 >= Bc) return;
  const int tid = threadIdx.x;

  // stage 32 rows (fp16, 16B chunks; clamped gather for OOB rows)
  for (int u = tid; u < RGB * 32; u += 256) {
    const int r = u >> 5, c = u & 31;
    const int rr = r0 + r;
    const int gr = g_bucket[bs + (rr < Bc ? rr : Bc - 1)];
    sA[u] = ((const uint4*)(Fh + (size_t)gr * 256))[c];
  }
  __syncthreads();

  const int wv = tid >> 6, lane = tid & 63;
  const int cc = c0 + lane;
  const int gq = g_bucket[bs + (cc < Bc ? cc : Bc - 1)];
  const uint4* fq = (const uint4*)(Fh + (size_t)gq * 256);
  const uint4* sw = sA + wv * 8 * 32;  // this wave's 8 rows

  float acc[8];
#pragma unroll
  for (int r = 0; r < 8; ++r) acc[r] = 0.0f;

  for (int k = 0; k < 32; k += 4) {
    // 4 independent gathers in flight per iteration
    const uint4 a0 = fq[k], a1 = fq[k + 1], a2 = fq[k + 2], a3 = fq[k + 3];
#pragma unroll
    for (int r = 0; r < 8; ++r) {
      float t = acc[r];
      t = dot8h(sw[r * 32 + k    ], a0, t);   // LDS wave-uniform broadcast
      t = dot8h(sw[r * 32 + k + 1], a1, t);
      t = dot8h(sw[r * 32 + k + 2], a2, t);
      t = dot8h(sw[r * 32 + k + 3], a3, t);
      acc[r] = t;
    }
  }

  if (cc < Bc) {
    float* outb = g_sims + g_soff[b];
#pragma unroll
    for (int r = 0; r < 8; ++r) {
      const int rr = r0 + wv * 8 + r;
      if (rr < Bc)
        outb[(size_t)rr * Bc + cc] = (rr == cc) ? -3.0e38f : acc[r] * 10.0f;
    }
  }
}

// ---- per-anchor: one wave; value-only argmax + dual-chain negatives ----
// (round-9 version — strictly leaner than round-6's)
__global__ __launch_bounds__(256) void k_anchor(
    const __half* __restrict__ Fh, const int* __restrict__ g_bucket,
    const int4* __restrict__ g_meta, const float* __restrict__ g_sims,
    float* __restrict__ g_part, int K) {
  __shared__ uint4 sA[4 * 32];        // 4 waves x 512B anchor rows
  const int wv = threadIdx.x >> 6;
  const int lane = threadIdx.x & 63;
  const int i = blockIdx.x * 4 + wv;  // K multiple of 4

  // stage anchor row into wave-private LDS (independent of meta)
  ((uint2*)sA)[wv * 64 + lane] = ((const uint2*)(Fh + (size_t)i * 256))[lane];
  const uint4* sw = sA + wv * 32;

  const int4 mt = g_meta[i];          // (bucket_start, bucket_size, loc, soff)
  const int bs = mt.x, B = mt.y;
  const int Bc = B < MAXBC ? B : MAXBC;
  int loc = mt.z;
  if (loc >= Bc) loc = 0;             // unreachable in practice
  const int n_pos = B - 1;
  const int n_neg = K - B;
  const float* simrow = g_sims + mt.w + (size_t)loc * Bc;

  // sim row -> 5 registers (Bc <= 320)
  float v[5];
#pragma unroll
  for (int rr = 0; rr < 5; ++rr) {
    const int t = lane + rr * 64;
    v[rr] = (t < Bc) ? simrow[t] : -3.4e38f;
  }

  int t6 = n_neg < MAXP ? n_neg : MAXP;
  if (t6 < 1) t6 = 1;
  int take = n_pos < t6 ? n_pos : t6;
  if (n_pos <= 0 || n_neg <= 0) take = 0;
  const int target = (take > 0) ? (n_neg < NEGK ? n_neg : NEGK) : 0;

  // ---- negatives first (kick off the gathers): dual independent chains ----
  const int s = lane & 3, g = lane >> 2;
  const int n0 = g, n1 = 16 + g;
  const uint64_t z0 = mix64(((uint64_t)(uint32_t)i << 32) | (uint32_t)n0);
  const uint64_t z1 = mix64(((uint64_t)(uint32_t)i << 32) | (uint32_t)n1);
  const unsigned int r0 = (unsigned int)(((uint64_t)(uint32_t)z0 * (uint64_t)n_neg) >> 32);
  const unsigned int r1 = (unsigned int)(((uint64_t)(uint32_t)z1 * (uint64_t)n_neg) >> 32);
  const int pos0 = (r0 < (unsigned int)bs) ? (int)r0 : (int)r0 + B;
  const int pos1 = (r1 < (unsigned int)bs) ? (int)r1 : (int)r1 + B;
  const bool pv0 = (n0 < target), pv1 = (n1 < target);
  const int j0 = pv0 ? g_bucket[pos0] : 0;
  const int j1 = pv1 ? g_bucket[pos1] : 0;
  const uint4* f0 = (const uint4*)(Fh + (size_t)j0 * 256);
  const uint4* f1 = (const uint4*)(Fh + (size_t)j1 * 256);
  float d0 = 0.0f, d1 = 0.0f;
#pragma unroll
  for (int k = 0; k < 8; ++k) {
    const uint4 aw = sw[k * 4 + s];   // LDS 4-address multicast (conflict-free)
    d0 = dot8h(f0[k * 4 + s], aw, d0);
    d1 = dot8h(f1[k * 4 + s], aw, d1);
  }
  d0 += __shfl_xor(d0, 1, 64); d0 += __shfl_xor(d0, 2, 64);
  d1 += __shfl_xor(d1, 1, 64); d1 += __shfl_xor(d1, 2, 64);
  float e = 0.0f;
  if (s == 0) {
    if (pv0) e += expf(d0 * 10.0f);
    if (pv1) e += expf(d1 * 10.0f);
  }
  const float wsum = wave_reduce_add(e);

  // ---- top-take positives: value-only max + exclude-by-equality ----
  float num = 0.0f;
  for (int r = 0; r < take; ++r) {
    float best = v[0];
#pragma unroll
    for (int c = 1; c < 5; ++c) best = fmaxf(best, v[c]);
#pragma unroll
    for (int o = 1; o < 64; o <<= 1) best = fmaxf(best, __shfl_xor(best, o, 64));
    num += expf(best);
#pragma unroll
    for (int c = 0; c < 5; ++c)
      if (v[c] == best) v[c] = -3.4e38f;
  }

  if (lane == 0) {
    float ls = 0.0f;
    if (take > 0) {
      const float denom = num + wsum;
      float ratio = denom > 0.0f ? num / denom : 0.0f;
      ratio = fmaxf(ratio, 1e-8f);
      ls = -logf(ratio);
    }
    g_part[i] = ls;                   // plain store, no atomics
  }
}

// ---- reduce 8192 per-anchor losses -> mean ----
__global__ __launch_bounds__(1024) void k_final(const float* __restrict__ g_part,
                                                float* __restrict__ out, int K) {
  __shared__ float s[16];
  float p = 0.0f;
  for (int t = threadIdx.x; t < K; t += 1024) p += g_part[t];
  p = wave_reduce_add(p);
  if ((threadIdx.x & 63) == 0) s[threadIdx.x >> 6] = p;
  __syncthreads();
  if (threadIdx.x == 0) {
    float tot = 0.0f;
#pragma unroll
    for (int w = 0; w < 16; ++w) tot += s[w];
    out[0] = tot / (float)K;
  }
}

extern "C" void kernel_launch(void* const* d_in, const int* in_sizes, int n_in,
                              void* d_out, int out_size, void* d_ws, size_t ws_size,
                              hipStream_t stream) {
  (void)n_in; (void)out_size; (void)ws_size;
  const float* F = (const float*)d_in[0];
  const int* labels = (const int*)d_in[1];
  const int K = in_sizes[1];  // 8192; D=256 hard-assumed
  float* out = (float*)d_out;

  char* ws = (char*)d_ws;
  size_t off = 0;
  int*   g_start  = (int*)(ws + off);   off += 512;
  int*   g_soff   = (int*)(ws + off);   off += 256;
  int*   g_bucket = (int*)(ws + off);   off += (size_t)K * 4;
  float* g_part   = (float*)(ws + off); off += (size_t)K * 4;
  off = (off + 255) & ~(size_t)255;
  int4*  g_meta   = (int4*)(ws + off);  off += (size_t)K * 16;
  __half* Fh      = (__half*)(ws + off); off += (size_t)K * 256 * 2;
  float* g_sims   = (float*)(ws + off);  off += (size_t)MAXBC * K * 4;

  k_prep<<<K / 4 + 1, 256, 0, stream>>>(F, labels, K, Fh, g_start, g_soff,
                                        g_bucket, g_meta);
  {
    dim3 grid(64, (MAXBC + RGB - 1) / RGB, (MAXBC + CGB - 1) / CGB);
    k_gram<<<grid, 256, 0, stream>>>(Fh, g_start, g_soff, g_bucket, g_sims);
  }
  k_anchor<<<K / 4, 256, 0, stream>>>(Fh, g_bucket, g_meta, g_sims, g_part, K);
  k_final<<<1, 1024, 0, stream>>>(g_part, out, K);
}